// Round 11
// baseline (16.984 us; speedup 1.0000x reference)
//
#include <hip/hip_runtime.h>
#include <math.h>

// ---- problem constants ----
#define NB    512   // batch
#define STATE 512
#define IMS   224
#define TSB   768   // 3*16*16
#define HGN   128
#define GN    256
#define WPITCH 65   // 64 + 1 pad
#define NPF   32    // W_hg float4 rows staged during phase 3 (of 48)

typedef float f32x4 __attribute__((ext_vector_type(4)));

// depth-1 (32->16) antialiased linear weights: taps at j = 2*o-1 + a
__device__ __forceinline__ void d1w(int o, float w[4]) {
    w[0] = 0.125f; w[1] = 0.375f; w[2] = 0.375f; w[3] = 0.125f;
    if (o == 0)  { w[0] = 0.f;      w[1] = 3.f/7.f; w[2] = 3.f/7.f; w[3] = 1.f/7.f; }
    if (o == 15) { w[0] = 1.f/7.f;  w[1] = 3.f/7.f; w[2] = 3.f/7.f; w[3] = 0.f; }
}
// depth-2 (64->16) weights: taps at j = 4*o-2 + a
__device__ __forceinline__ void d2w(int o, float w[8]) {
    const float s = 1.f/32.f;
    w[0]=1*s; w[1]=3*s; w[2]=5*s; w[3]=7*s; w[4]=7*s; w[5]=5*s; w[6]=3*s; w[7]=1*s;
    if (o == 0)  { const float t=1.f/28.f; w[0]=0.f; w[1]=0.f; w[2]=5*t; w[3]=7*t; w[4]=7*t; w[5]=5*t; w[6]=3*t; w[7]=1*t; }
    if (o == 15) { const float t=1.f/28.f; w[0]=1*t; w[1]=3*t; w[2]=5*t; w[3]=7*t; w[4]=7*t; w[5]=5*t; w[6]=0.f; w[7]=0.f; }
}

#define FMA4(acc, sc, w4) \
    acc.x += (sc) * (w4).x; acc.y += (sc) * (w4).y; \
    acc.z += (sc) * (w4).z; acc.w += (sc) * (w4).w;
#define FMA4V(acc, sc, wv) \
    acc.x += (sc) * (wv)[0]; acc.y += (sc) * (wv)[1]; \
    acc.z += (sc) * (wv)[2]; acc.w += (sc) * (wv)[3];

// Fully fused: loc -> glimpses -> hg -> hl -> g.  2 samples per block, 512 thr.
// T14 async-STAGE, non-overlapping live ranges (R10 lesson: asm-pinned tuples
// must stay well under the 256-VGPR budget):
//   wv[32]   (W_hg rows 0..31)  issued pre-phase-3, consumed phase 4, dead.
//   ag/bg[32] (W_gs/W_ls)       issued top of phase 5, consumed phase 6.
// Only vmcnt(0) waits (robust against compiler-inserted vmem ops).
__global__ __launch_bounds__(512) void fused_attn(
    const float* __restrict__ out_state,  // [512][512]
    const float* __restrict__ img,        // [512][224][224]
    const float* __restrict__ W_loc, const float* __restrict__ b_loc,
    const float* __restrict__ W_hg,  const float* __restrict__ b_hg,
    const float* __restrict__ W_hl,  const float* __restrict__ b_hl,
    const float* __restrict__ W_gs,  const float* __restrict__ b_gs,
    const float* __restrict__ W_ls,  const float* __restrict__ b_ls,
    float* __restrict__ out)              // [512][256]
{
    __shared__ float win[2][64 * WPITCH];   // 33.3 KB
    __shared__ float gl[2][TSB];            // 6 KB
    __shared__ float s_hg[2][HGN];
    __shared__ float s_hl[2][HGN];
    __shared__ float part4[2][16][HGN];     // 16 KB
    __shared__ float part6[2][8][GN];       // 16 KB
    __shared__ float red[8][2];
    __shared__ float s_loc[2][2];
    __shared__ int   s_li[2][2];

    const int t  = threadIdx.x;
    const int b0 = blockIdx.x * 2;

    // phase-4/6 thread mappings (needed for stage addresses)
    const int cg4 = t & 31, q4 = t >> 5;     // 4 cols of 128, 16 k-groups of 48
    const int cg6 = t & 63, q6 = t >> 6;     // 4 cols of 256, 8 j-groups of 16
    const float* wp4 = W_hg + (size_t)(q4 * 48) * HGN + cg4 * 4;
    const float* wgs = W_gs + (size_t)(q6 * 16) * GN + cg6 * 4;
    const float* wls = W_ls + (size_t)(q6 * 16) * GN + cg6 * 4;

    // ---- phase 1: loc = clip(output @ W_loc + b_loc)
    {
        int s = t >> 8, k = t & 255;
        const float* orow = out_state + (size_t)(b0 + s) * STATE;
        float x0 = orow[k], x1 = orow[k + 256];
        float a0 = x0 * W_loc[k*2]     + x1 * W_loc[(k+256)*2];
        float a1 = x0 * W_loc[k*2 + 1] + x1 * W_loc[(k+256)*2 + 1];
        for (int off = 32; off; off >>= 1) {
            a0 += __shfl_down(a0, off);
            a1 += __shfl_down(a1, off);
        }
        if ((t & 63) == 0) { red[t>>6][0] = a0; red[t>>6][1] = a1; }
    }
    __syncthreads();
    if ((t & 255) == 0) {
        int s = t >> 8;
        float l0 = red[4*s][0]+red[4*s+1][0]+red[4*s+2][0]+red[4*s+3][0] + b_loc[0];
        float l1 = red[4*s][1]+red[4*s+1][1]+red[4*s+2][1]+red[4*s+3][1] + b_loc[1];
        l0 = fminf(fmaxf(l0, -1.f), 1.f);
        l1 = fminf(fmaxf(l1, -1.f), 1.f);
        s_loc[s][0] = l0; s_loc[s][1] = l1;
        s_li[s][0] = (int)rintf((l0 + 1.f) * 0.5f * (float)IMS);
        s_li[s][1] = (int)rintf((l1 + 1.f) * 0.5f * (float)IMS);
    }
    __syncthreads();

    // ---- phase 2: 64x64 windows centered at loc, zero outside image
    #pragma unroll
    for (int i = 0; i < 16; ++i) {
        int idx = t + i * 512;
        int s = idx >> 12, rem = idx & 4095;
        int r = rem >> 6, c = rem & 63;
        int rr = s_li[s][0] - 32 + r, cc = s_li[s][1] - 32 + c;
        float v = 0.f;
        if ((unsigned)rr < (unsigned)IMS && (unsigned)cc < (unsigned)IMS)
            v = img[(size_t)(b0 + s) * IMS * IMS + rr * IMS + cc];
        win[s][r * WPITCH + c] = v;
    }
    __syncthreads();

    // ---- T14 stage-issue: first 32 W_hg float4 in flight under phase 3
    f32x4 wv[NPF];
    #pragma unroll
    for (int k = 0; k < NPF; ++k) {
        asm volatile("global_load_dwordx4 %0, %1, off"
                     : "=&v"(wv[k])
                     : "v"(wp4 + (size_t)k * HGN));
    }

    // ---- phase 3: 3-depth glimpses -> gl LDS (LDS/VALU only; stream in flight)
    {
        int s = t >> 8, p = t & 255, r = p >> 4, c = p & 15;
        const float* w = win[s];
        gl[s][p] = w[(24 + r) * WPITCH + (24 + c)];
        {
            float wr[4], wc[4];
            d1w(r, wr); d1w(c, wc);
            int jr0 = 16 + 2*r - 1, jc0 = 16 + 2*c - 1;
            float acc = 0.f;
            #pragma unroll
            for (int a = 0; a < 4; ++a) {
                float rowsum = 0.f;
                #pragma unroll
                for (int bb = 0; bb < 4; ++bb)
                    rowsum += wc[bb] * w[(jr0 + a) * WPITCH + (jc0 + bb)];
                acc += wr[a] * rowsum;
            }
            gl[s][256 + p] = acc;
        }
        {
            float wr[8], wc[8];
            d2w(r, wr); d2w(c, wc);
            int jr0 = 4*r - 2, jc0 = 4*c - 2;
            float acc = 0.f;
            #pragma unroll
            for (int a = 0; a < 8; ++a) {
                int jr = min(max(jr0 + a, 0), 63);
                float rowsum = 0.f;
                #pragma unroll
                for (int bb = 0; bb < 8; ++bb) {
                    int jc = min(max(jc0 + bb, 0), 63);
                    rowsum += wc[bb] * w[jr * WPITCH + jc];
                }
                acc += wr[a] * rowsum;
            }
            gl[s][512 + p] = acc;
        }
    }
    __syncthreads();

    // ---- phase 4: hg partials. k<NPF from staged regs, rest from L2.
    {
        // staged loads have landed (barrier drained vmcnt); fence reg-only FMAs
        asm volatile("s_waitcnt vmcnt(0)" ::: "memory");
        __builtin_amdgcn_sched_barrier(0);

        const float* g0 = gl[0] + q4 * 48;
        const float* g1 = gl[1] + q4 * 48;
        float4 acc0 = make_float4(0.f,0.f,0.f,0.f);
        float4 acc1 = acc0;
        #pragma unroll
        for (int k = 0; k < NPF; ++k) {
            float a = g0[k], b = g1[k];
            FMA4V(acc0, a, wv[k]);
            FMA4V(acc1, b, wv[k]);
        }
        #pragma unroll 8
        for (int k = NPF; k < 48; ++k) {
            float4 w4 = *(const float4*)(wp4 + (size_t)k * HGN);
            FMA4(acc0, g0[k], w4);
            FMA4(acc1, g1[k], w4);
        }
        *(float4*)&part4[0][q4][cg4 * 4] = acc0;
        *(float4*)&part4[1][q4][cg4 * 4] = acc1;
    }
    __syncthreads();

    // ---- phase 5: stage phase-6 weights, then reduce hg partials + hl.
    // wv is dead; ag/bg reuse that register space (non-overlapping ranges).
    f32x4 ag[16], bg[16];
    #pragma unroll
    for (int j = 0; j < 16; ++j) {
        asm volatile("global_load_dwordx4 %0, %1, off"
                     : "=&v"(ag[j]) : "v"(wgs + (size_t)j * GN));
        asm volatile("global_load_dwordx4 %0, %1, off"
                     : "=&v"(bg[j]) : "v"(wls + (size_t)j * GN));
    }
    {
        int u = t & 255, s = u >> 7, col = u & 127;
        if (t < 256) {
            float a = b_hg[col];
            #pragma unroll
            for (int q = 0; q < 16; ++q) a += part4[s][q][col];
            s_hg[s][col] = fmaxf(a, 0.f);
        } else {
            float l0 = s_loc[s][0], l1 = s_loc[s][1];
            s_hl[s][col] = fmaxf(l0 * W_hl[col] + l1 * W_hl[HGN + col] + b_hl[col], 0.f);
        }
    }
    __syncthreads();

    // ---- phase 6: g partials = pure FMA from staged ag/bg
    {
        asm volatile("s_waitcnt vmcnt(0)" ::: "memory");
        __builtin_amdgcn_sched_barrier(0);
        float4 acc0 = make_float4(0.f,0.f,0.f,0.f);
        float4 acc1 = acc0;
        #pragma unroll
        for (int j = 0; j < 16; ++j) {
            int jj = q6 * 16 + j;
            float hga = s_hg[0][jj], hgb = s_hg[1][jj];
            float hla = s_hl[0][jj], hlb = s_hl[1][jj];
            FMA4V(acc0, hga, ag[j]); FMA4V(acc0, hla, bg[j]);
            FMA4V(acc1, hgb, ag[j]); FMA4V(acc1, hlb, bg[j]);
        }
        *(float4*)&part6[0][q6][cg6 * 4] = acc0;
        *(float4*)&part6[1][q6][cg6 * 4] = acc1;
    }
    __syncthreads();
    {
        int s = t >> 8, n = t & 255;
        float a = b_gs[n] + b_ls[n];
        #pragma unroll
        for (int q = 0; q < 8; ++q) a += part6[s][q][n];
        out[(size_t)(b0 + s) * GN + n] = fmaxf(a, 0.f);
    }
}

extern "C" void kernel_launch(void* const* d_in, const int* in_sizes, int n_in,
                              void* d_out, int out_size, void* d_ws, size_t ws_size,
                              hipStream_t stream) {
    const float* out_state = (const float*)d_in[0];
    const float* img       = (const float*)d_in[1];
    const float* W_loc     = (const float*)d_in[2];
    const float* b_loc     = (const float*)d_in[3];
    const float* W_hg      = (const float*)d_in[4];
    const float* b_hg      = (const float*)d_in[5];
    const float* W_hl      = (const float*)d_in[6];
    const float* b_hl      = (const float*)d_in[7];
    const float* W_gs      = (const float*)d_in[8];
    const float* b_gs      = (const float*)d_in[9];
    const float* W_ls      = (const float*)d_in[10];
    const float* b_ls      = (const float*)d_in[11];
    float* out = (float*)d_out;

    hipLaunchKernelGGL(fused_attn, dim3(NB/2), dim3(512), 0, stream,
                       out_state, img, W_loc, b_loc, W_hg, b_hg,
                       W_hl, b_hl, W_gs, b_gs, W_ls, b_ls, out);
}

// Round 12
// 16.287 us; speedup vs baseline: 1.0428x; 1.0428x over previous
//
#include <hip/hip_runtime.h>
#include <math.h>

// ---- problem constants ----
#define NB    512   // batch
#define STATE 512
#define IMS   224
#define TSB   768   // 3*16*16
#define HGN   128
#define GN    256
#define WPITCH 65   // 64 + 1 pad
#define NPF   32    // W_hg float4 rows staged during phase 3 (of 48)

typedef float f32x4 __attribute__((ext_vector_type(4)));

// depth-1 (32->16) antialiased linear weights: taps at j = 2*o-1 + a
__device__ __forceinline__ void d1w(int o, float w[4]) {
    w[0] = 0.125f; w[1] = 0.375f; w[2] = 0.375f; w[3] = 0.125f;
    if (o == 0)  { w[0] = 0.f;      w[1] = 3.f/7.f; w[2] = 3.f/7.f; w[3] = 1.f/7.f; }
    if (o == 15) { w[0] = 1.f/7.f;  w[1] = 3.f/7.f; w[2] = 3.f/7.f; w[3] = 0.f; }
}
// depth-2 (64->16) weights: taps at j = 4*o-2 + a
__device__ __forceinline__ void d2w(int o, float w[8]) {
    const float s = 1.f/32.f;
    w[0]=1*s; w[1]=3*s; w[2]=5*s; w[3]=7*s; w[4]=7*s; w[5]=5*s; w[6]=3*s; w[7]=1*s;
    if (o == 0)  { const float t=1.f/28.f; w[0]=0.f; w[1]=0.f; w[2]=5*t; w[3]=7*t; w[4]=7*t; w[5]=5*t; w[6]=3*t; w[7]=1*t; }
    if (o == 15) { const float t=1.f/28.f; w[0]=1*t; w[1]=3*t; w[2]=5*t; w[3]=7*t; w[4]=7*t; w[5]=5*t; w[6]=0.f; w[7]=0.f; }
}

#define FMA4(acc, sc, w4) \
    acc.x += (sc) * (w4).x; acc.y += (sc) * (w4).y; \
    acc.z += (sc) * (w4).z; acc.w += (sc) * (w4).w;
#define FMA4V(acc, sc, wv) \
    acc.x += (sc) * (wv)[0]; acc.y += (sc) * (wv)[1]; \
    acc.z += (sc) * (wv)[2]; acc.w += (sc) * (wv)[3];

// Fully fused: loc -> glimpses -> hg -> hl -> g.  2 samples per block, 512 thr.
// R9 (best known): T14 async-STAGE of W_hg[0:32] via inline-asm global_load,
// issued pre-phase-3 so the L2 weight stream hides under glimpse compute
// (pure LDS/VALU). Consumed in phase 4 after vmcnt(0) + sched_barrier(0).
// Staged live range disjoint from everything else; no other asm staging
// (placements overlapping compiler-visible vmem loads over-drain, R10/R11).
__global__ __launch_bounds__(512) void fused_attn(
    const float* __restrict__ out_state,  // [512][512]
    const float* __restrict__ img,        // [512][224][224]
    const float* __restrict__ W_loc, const float* __restrict__ b_loc,
    const float* __restrict__ W_hg,  const float* __restrict__ b_hg,
    const float* __restrict__ W_hl,  const float* __restrict__ b_hl,
    const float* __restrict__ W_gs,  const float* __restrict__ b_gs,
    const float* __restrict__ W_ls,  const float* __restrict__ b_ls,
    float* __restrict__ out)              // [512][256]
{
    __shared__ float win[2][64 * WPITCH];   // 33.3 KB
    __shared__ float gl[2][TSB];            // 6 KB
    __shared__ float s_hg[2][HGN];
    __shared__ float s_hl[2][HGN];
    __shared__ float part4[2][16][HGN];     // 16 KB
    __shared__ float part6[2][8][GN];       // 16 KB
    __shared__ float red[8][2];
    __shared__ float s_loc[2][2];
    __shared__ int   s_li[2][2];

    const int t  = threadIdx.x;
    const int b0 = blockIdx.x * 2;

    // phase-4 thread mapping (needed for the prefetch addresses)
    const int cg4 = t & 31, q4 = t >> 5;     // 4 cols of 128, 16 k-groups of 48
    const float* wp4 = W_hg + (size_t)(q4 * 48) * HGN + cg4 * 4;

    // ---- phase 1: loc = clip(output @ W_loc + b_loc)
    {
        int s = t >> 8, k = t & 255;
        const float* orow = out_state + (size_t)(b0 + s) * STATE;
        float x0 = orow[k], x1 = orow[k + 256];
        float a0 = x0 * W_loc[k*2]     + x1 * W_loc[(k+256)*2];
        float a1 = x0 * W_loc[k*2 + 1] + x1 * W_loc[(k+256)*2 + 1];
        for (int off = 32; off; off >>= 1) {
            a0 += __shfl_down(a0, off);
            a1 += __shfl_down(a1, off);
        }
        if ((t & 63) == 0) { red[t>>6][0] = a0; red[t>>6][1] = a1; }
    }
    __syncthreads();
    if ((t & 255) == 0) {
        int s = t >> 8;
        float l0 = red[4*s][0]+red[4*s+1][0]+red[4*s+2][0]+red[4*s+3][0] + b_loc[0];
        float l1 = red[4*s][1]+red[4*s+1][1]+red[4*s+2][1]+red[4*s+3][1] + b_loc[1];
        l0 = fminf(fmaxf(l0, -1.f), 1.f);
        l1 = fminf(fmaxf(l1, -1.f), 1.f);
        s_loc[s][0] = l0; s_loc[s][1] = l1;
        s_li[s][0] = (int)rintf((l0 + 1.f) * 0.5f * (float)IMS);
        s_li[s][1] = (int)rintf((l1 + 1.f) * 0.5f * (float)IMS);
    }
    __syncthreads();

    // ---- phase 2: 64x64 windows centered at loc, zero outside image
    #pragma unroll
    for (int i = 0; i < 16; ++i) {
        int idx = t + i * 512;
        int s = idx >> 12, rem = idx & 4095;
        int r = rem >> 6, c = rem & 63;
        int rr = s_li[s][0] - 32 + r, cc = s_li[s][1] - 32 + c;
        float v = 0.f;
        if ((unsigned)rr < (unsigned)IMS && (unsigned)cc < (unsigned)IMS)
            v = img[(size_t)(b0 + s) * IMS * IMS + rr * IMS + cc];
        win[s][r * WPITCH + c] = v;
    }
    __syncthreads();

    // ---- T14 stage-issue: first 32 W_hg float4 in flight under phase 3
    f32x4 wv[NPF];
    #pragma unroll
    for (int k = 0; k < NPF; ++k) {
        asm volatile("global_load_dwordx4 %0, %1, off"
                     : "=&v"(wv[k])
                     : "v"(wp4 + (size_t)k * HGN));
    }

    // ---- phase 3: 3-depth glimpses -> gl LDS (LDS/VALU only; stream in flight)
    {
        int s = t >> 8, p = t & 255, r = p >> 4, c = p & 15;
        const float* w = win[s];
        gl[s][p] = w[(24 + r) * WPITCH + (24 + c)];
        {
            float wr[4], wc[4];
            d1w(r, wr); d1w(c, wc);
            int jr0 = 16 + 2*r - 1, jc0 = 16 + 2*c - 1;
            float acc = 0.f;
            #pragma unroll
            for (int a = 0; a < 4; ++a) {
                float rowsum = 0.f;
                #pragma unroll
                for (int bb = 0; bb < 4; ++bb)
                    rowsum += wc[bb] * w[(jr0 + a) * WPITCH + (jc0 + bb)];
                acc += wr[a] * rowsum;
            }
            gl[s][256 + p] = acc;
        }
        {
            float wr[8], wc[8];
            d2w(r, wr); d2w(c, wc);
            int jr0 = 4*r - 2, jc0 = 4*c - 2;
            float acc = 0.f;
            #pragma unroll
            for (int a = 0; a < 8; ++a) {
                int jr = min(max(jr0 + a, 0), 63);
                float rowsum = 0.f;
                #pragma unroll
                for (int bb = 0; bb < 8; ++bb) {
                    int jc = min(max(jc0 + bb, 0), 63);
                    rowsum += wc[bb] * w[jr * WPITCH + jc];
                }
                acc += wr[a] * rowsum;
            }
            gl[s][512 + p] = acc;
        }
    }
    __syncthreads();

    // ---- phase 4: hg partials. k<NPF from staged regs, rest from L2.
    {
        // ensure staged loads have landed; block reg-only FMA hoisting (rule #18)
        asm volatile("s_waitcnt vmcnt(0)" ::: "memory");
        __builtin_amdgcn_sched_barrier(0);

        const float* g0 = gl[0] + q4 * 48;
        const float* g1 = gl[1] + q4 * 48;
        float4 acc0 = make_float4(0.f,0.f,0.f,0.f);
        float4 acc1 = acc0;
        #pragma unroll
        for (int k = 0; k < NPF; ++k) {
            float a = g0[k], b = g1[k];
            FMA4V(acc0, a, wv[k]);
            FMA4V(acc1, b, wv[k]);
        }
        #pragma unroll 8
        for (int k = NPF; k < 48; ++k) {
            float4 w4 = *(const float4*)(wp4 + (size_t)k * HGN);
            FMA4(acc0, g0[k], w4);
            FMA4(acc1, g1[k], w4);
        }
        *(float4*)&part4[0][q4][cg4 * 4] = acc0;
        *(float4*)&part4[1][q4][cg4 * 4] = acc1;
    }
    __syncthreads();

    // ---- phase 5: reduce hg partials (t<256) + hl (t>=256)
    {
        int u = t & 255, s = u >> 7, col = u & 127;
        if (t < 256) {
            float a = b_hg[col];
            #pragma unroll
            for (int q = 0; q < 16; ++q) a += part4[s][q][col];
            s_hg[s][col] = fmaxf(a, 0.f);
        } else {
            float l0 = s_loc[s][0], l1 = s_loc[s][1];
            s_hl[s][col] = fmaxf(l0 * W_hl[col] + l1 * W_hl[HGN + col] + b_hl[col], 0.f);
        }
    }
    __syncthreads();

    // ---- phase 6: g partials, weights shared across samples
    {
        int cg = t & 63, q = t >> 6;
        const float* wgs = W_gs + (size_t)(q * 16) * GN + cg * 4;
        const float* wls = W_ls + (size_t)(q * 16) * GN + cg * 4;
        float4 acc0 = make_float4(0.f,0.f,0.f,0.f);
        float4 acc1 = acc0;
        #pragma unroll 8
        for (int j = 0; j < 16; ++j) {
            float4 a4 = *(const float4*)(wgs + (size_t)j * GN);
            float4 b4 = *(const float4*)(wls + (size_t)j * GN);
            int jj = q * 16 + j;
            float hga = s_hg[0][jj], hgb = s_hg[1][jj];
            float hla = s_hl[0][jj], hlb = s_hl[1][jj];
            FMA4(acc0, hga, a4); FMA4(acc0, hla, b4);
            FMA4(acc1, hgb, a4); FMA4(acc1, hlb, b4);
        }
        *(float4*)&part6[0][q][cg * 4] = acc0;
        *(float4*)&part6[1][q][cg * 4] = acc1;
    }
    __syncthreads();
    {
        int s = t >> 8, n = t & 255;
        float a = b_gs[n] + b_ls[n];
        #pragma unroll
        for (int q = 0; q < 8; ++q) a += part6[s][q][n];
        out[(size_t)(b0 + s) * GN + n] = fmaxf(a, 0.f);
    }
}

extern "C" void kernel_launch(void* const* d_in, const int* in_sizes, int n_in,
                              void* d_out, int out_size, void* d_ws, size_t ws_size,
                              hipStream_t stream) {
    const float* out_state = (const float*)d_in[0];
    const float* img       = (const float*)d_in[1];
    const float* W_loc     = (const float*)d_in[2];
    const float* b_loc     = (const float*)d_in[3];
    const float* W_hg      = (const float*)d_in[4];
    const float* b_hg      = (const float*)d_in[5];
    const float* W_hl      = (const float*)d_in[6];
    const float* b_hl      = (const float*)d_in[7];
    const float* W_gs      = (const float*)d_in[8];
    const float* b_gs      = (const float*)d_in[9];
    const float* W_ls      = (const float*)d_in[10];
    const float* b_ls      = (const float*)d_in[11];
    float* out = (float*)d_out;

    hipLaunchKernelGGL(fused_attn, dim3(NB/2), dim3(512), 0, stream,
                       out_state, img, W_loc, b_loc, W_hg, b_hg,
                       W_hl, b_hl, W_gs, b_gs, W_ls, b_ls, out);
}